// Round 5
// baseline (316.877 us; speedup 1.0000x reference)
//
#include <hip/hip_runtime.h>
#include <hip/hip_bf16.h>
#include <hip/hip_fp8.h>
#include <stdint.h>

#define Nn 8192
#define TWO_N 16384
#define INV_TAU 2.0f
#define EXP2_SCALE 2.885390081777927f   /* INV_TAU * log2(e) */

typedef unsigned short u16;
typedef unsigned char u8;
typedef __bf16 bf16x8 __attribute__((ext_vector_type(8)));
typedef float f32x4 __attribute__((ext_vector_type(4)));
typedef int i32x8 __attribute__((ext_vector_type(8)));

typedef const __attribute__((address_space(1))) void* gas_ptr;
typedef __attribute__((address_space(3))) void* las_ptr;

__device__ __forceinline__ void async_copy16(const void* g, void* l) {
  __builtin_amdgcn_global_load_lds((gas_ptr)g, (las_ptr)l, 16, 0, 0);
}

// v_exp_f32: D = 2^S0 (hardware transcendental)
__device__ __forceinline__ float hw_exp2(float x) {
  return __builtin_amdgcn_exp2f(x);
}

// ---------------- fused MLP + normalize + fp8 emit ---------------------------
// (round-3 version, reverted: 256 blocks x 64 rows; round-4's 512x32 split
//  cost ~3 us from doubled W restaging with no TLP payoff)
__global__ __launch_bounds__(256)
void mlp_norm(const float* __restrict__ z1, const float* __restrict__ z2,
              const float* __restrict__ W1, const float* __restrict__ b1,
              const float* __restrict__ W2, const float* __restrict__ b2,
              u8* __restrict__ Mf8, float* __restrict__ snorm,
              float* __restrict__ rsum) {
  __shared__ __bf16 sZ[64 * 64];    // 8 KB  (layer1 A; reduce scratch later)
  __shared__ __bf16 sW[256 * 64];   // 32 KB (W chunk, both layers)
  __shared__ __bf16 sH[64 * 256];   // 32 KB (H1, full K for layer 2)
  const int bx = blockIdx.x;
  const int i0 = bx * 64;
  const float* Zsrc = (bx < 128) ? (z1 + (size_t)i0 * 256)
                                 : (z2 + (size_t)(i0 - Nn) * 256);
  const int t = threadIdx.x;
  const int lane = t & 63, wave = t >> 6;
  const int wn = wave * 64;
  const int fr = lane >> 4, fc = lane & 15;
  const int sw = fc & 7;

  if (t < 64) rsum[i0 + t] = 0.f;

  f32x4 acc[4][4];
#pragma unroll
  for (int a = 0; a < 4; a++)
#pragma unroll
    for (int b = 0; b < 4; b++) acc[a][b] = (f32x4){0.f, 0.f, 0.f, 0.f};

  // ---- layer 1 ----
  for (int k0 = 0; k0 < 256; k0 += 64) {
    __syncthreads();
#pragma unroll
    for (int it = 0; it < 2; ++it) {               // Z: 512 granules
      int c = t + 256 * it;
      int row = c >> 3, g = (c & 7) ^ (row & 7);
      const float* s = Zsrc + (size_t)row * 256 + k0 + g * 8;
      float4 a0 = *(const float4*)s, a1 = *(const float4*)(s + 4);
      bf16x8 v = {(__bf16)a0.x, (__bf16)a0.y, (__bf16)a0.z, (__bf16)a0.w,
                  (__bf16)a1.x, (__bf16)a1.y, (__bf16)a1.z, (__bf16)a1.w};
      *(bf16x8*)&sZ[c * 8] = v;
    }
#pragma unroll
    for (int it = 0; it < 8; ++it) {               // W1: 2048 granules
      int c = t + 256 * it;
      int row = c >> 3, g = (c & 7) ^ (row & 7);
      const float* s = W1 + (size_t)row * 256 + k0 + g * 8;
      float4 a0 = *(const float4*)s, a1 = *(const float4*)(s + 4);
      bf16x8 v = {(__bf16)a0.x, (__bf16)a0.y, (__bf16)a0.z, (__bf16)a0.w,
                  (__bf16)a1.x, (__bf16)a1.y, (__bf16)a1.z, (__bf16)a1.w};
      *(bf16x8*)&sW[c * 8] = v;
    }
    __syncthreads();
#pragma unroll
    for (int ks = 0; ks < 2; ++ks) {
      bf16x8 af[4], bfr[4];
#pragma unroll
      for (int mi = 0; mi < 4; mi++)
        af[mi] = *(const bf16x8*)&sZ[(mi * 16 + fc) * 64 + (((ks * 4 + fr) ^ sw) * 8)];
#pragma unroll
      for (int ni = 0; ni < 4; ni++)
        bfr[ni] = *(const bf16x8*)&sW[(wn + ni * 16 + fc) * 64 + (((ks * 4 + fr) ^ sw) * 8)];
#pragma unroll
      for (int mi = 0; mi < 4; mi++)
#pragma unroll
        for (int ni = 0; ni < 4; ni++)
          acc[mi][ni] = __builtin_amdgcn_mfma_f32_16x16x32_bf16(af[mi], bfr[ni], acc[mi][ni], 0, 0, 0);
    }
  }

  // layer-1 epilogue: bias + elu -> bf16 into sH (granule-xor swizzled rows)
  {
    float bv[4];
#pragma unroll
    for (int ni = 0; ni < 4; ni++) bv[ni] = b1[wn + ni * 16 + fc];
#pragma unroll
    for (int mi = 0; mi < 4; mi++)
#pragma unroll
      for (int ni = 0; ni < 4; ni++) {
        int col = wn + ni * 16 + fc;
        int gc = col >> 3;
#pragma unroll
        for (int r = 0; r < 4; r++) {
          int row = mi * 16 + fr * 4 + r;
          float v = acc[mi][ni][r] + bv[ni];
          v = v > 0.f ? v : (__expf(v) - 1.f);
          int pos = (gc & 24) | ((gc & 7) ^ (row & 7));
          sH[row * 256 + pos * 8 + (col & 7)] = (__bf16)v;
          acc[mi][ni][r] = 0.f;
        }
      }
  }

  // ---- layer 2 (A = sH, resident full-K) ----
  for (int k0 = 0; k0 < 256; k0 += 64) {
    __syncthreads();   // also guarantees: all sH writes done before first read
#pragma unroll
    for (int it = 0; it < 8; ++it) {               // W2: 2048 granules
      int c = t + 256 * it;
      int row = c >> 3, g = (c & 7) ^ (row & 7);
      const float* s = W2 + (size_t)row * 256 + k0 + g * 8;
      float4 a0 = *(const float4*)s, a1 = *(const float4*)(s + 4);
      bf16x8 v = {(__bf16)a0.x, (__bf16)a0.y, (__bf16)a0.z, (__bf16)a0.w,
                  (__bf16)a1.x, (__bf16)a1.y, (__bf16)a1.z, (__bf16)a1.w};
      *(bf16x8*)&sW[c * 8] = v;
    }
    __syncthreads();
    const int kgb = k0 >> 3;
#pragma unroll
    for (int ks = 0; ks < 2; ++ks) {
      bf16x8 af[4], bfr[4];
#pragma unroll
      for (int mi = 0; mi < 4; mi++)
        af[mi] = *(const bf16x8*)&sH[(mi * 16 + fc) * 256 + (kgb + (((ks * 4 + fr) ^ sw))) * 8];
#pragma unroll
      for (int ni = 0; ni < 4; ni++)
        bfr[ni] = *(const bf16x8*)&sW[(wn + ni * 16 + fc) * 64 + (((ks * 4 + fr) ^ sw) * 8)];
#pragma unroll
      for (int mi = 0; mi < 4; mi++)
#pragma unroll
        for (int ni = 0; ni < 4; ni++)
          acc[mi][ni] = __builtin_amdgcn_mfma_f32_16x16x32_bf16(af[mi], bfr[ni], acc[mi][ni], 0, 0, 0);
    }
  }

  // ---- epilogue: bias, cross-wave row-norm, fp8 emit, snorm ----
  float bv[4];
#pragma unroll
  for (int ni = 0; ni < 4; ni++) bv[ni] = b2[wn + ni * 16 + fc];

  __syncthreads();                 // sZ dead; reuse as reduce scratch
  float* red = (float*)sZ;         // [64 rows][4 waves]
  float* red2 = red + 256;

#pragma unroll
  for (int mi = 0; mi < 4; mi++) {
    float ssq[4] = {0.f, 0.f, 0.f, 0.f};
#pragma unroll
    for (int ni = 0; ni < 4; ni++)
#pragma unroll
      for (int r = 0; r < 4; r++) {
        float v = acc[mi][ni][r] + bv[ni];
        acc[mi][ni][r] = v;
        ssq[r] += v * v;
      }
#pragma unroll
    for (int r = 0; r < 4; r++) {
      float v = ssq[r];
#pragma unroll
      for (int off = 1; off < 16; off <<= 1) v += __shfl_xor(v, off, 16);
      if (fc == 0) red[(mi * 16 + fr * 4 + r) * 4 + wave] = v;
    }
  }
  __syncthreads();

#pragma unroll
  for (int mi = 0; mi < 4; mi++) {
    float ssq2[4] = {0.f, 0.f, 0.f, 0.f};
#pragma unroll
    for (int r = 0; r < 4; r++) {
      int row = mi * 16 + fr * 4 + r;
      float ss = red[row * 4] + red[row * 4 + 1] + red[row * 4 + 2] + red[row * 4 + 3];
      float rn = 1.f / fmaxf(sqrtf(ss), 1e-12f);
#pragma unroll
      for (int ni = 0; ni < 4; ni++) {
        float v = acc[mi][ni][r] * rn;
        __hip_fp8_e4m3 q(v);
        Mf8[(size_t)(i0 + row) * 256 + wn + ni * 16 + fc] = q.__x;
        float fv = (float)q;
        ssq2[r] += fv * fv;
      }
    }
#pragma unroll
    for (int r = 0; r < 4; r++) {
      float v = ssq2[r];
#pragma unroll
      for (int off = 1; off < 16; off <<= 1) v += __shfl_xor(v, off, 16);
      if (fc == 0) red2[(mi * 16 + fr * 4 + r) * 4 + wave] = v;
    }
  }
  __syncthreads();
  if (t < 64)
    snorm[i0 + t] = red2[t * 4] + red2[t * 4 + 1] + red2[t * 4 + 2] + red2[t * 4 + 3];
}

// ---------------- symmetric Gram, MX fp8 K=128, A-in-regs -------------------
// v4: SINGLE-buffered B (32 KB LDS) -> 4 independent blocks/CU (16 waves/CU,
// 4/SIMD), was 2. Same 128x128 tiles, same per-wave MFMA density, same atomic
// count as the 83-us round-3 version -- the only variable is independent-block
// TLP. Staging latency per tile is now exposed between two barriers, but four
// uncorrelated blocks per CU fill each other's stalls (Mf8 is 4 MB =
// L2-resident, so the exposed wait is a few hundred cycles).
__global__ __launch_bounds__(256, 4)
void gram_sym(const u8* __restrict__ Mf8, float* __restrict__ rsum) {
  __shared__ u8 sB8[128 * 256];   // 32 KB, single buffer
  const int t = threadIdx.x;
  const int lane = t & 63, wave = t >> 6;
  const int wm = (wave >> 1) * 64, wn = (wave & 1) * 64;
  const int fr = lane >> 4, fc = lane & 15;

  // ---- strip mapping (band closed form), long strips dispatched first ----
  int f = 2111 - blockIdx.x;
  int b = 0;
  while (f >= 2 * (b + 1) * (b + 2)) ++b;
  int rem = f - 2 * b * (b + 1);
  int r = rem / (b + 1);
  int q = rem - r * (b + 1);
  int k = 4 * b + 1 + r;
  const int i_t = 128 - k;
  const int jt0 = i_t + 4 * q;
  const int L = min(4, k - 4 * q);
  const int i0 = i_t * 128;

  // gather A fragments into registers (L2/L3-resident; once per strip)
  i32x8 afr[4][2];
  {
    const u8* Ag = Mf8 + (size_t)i0 * 256;
#pragma unroll
    for (int mi = 0; mi < 4; ++mi) {
      const u8* rp = Ag + (size_t)(wm + mi * 16 + fc) * 256 + fr * 32;
#pragma unroll
      for (int kb = 0; kb < 2; ++kb) {
        int4 lo = *(const int4*)(rp + kb * 128);
        int4 hi = *(const int4*)(rp + kb * 128 + 16);
        afr[mi][kb] = (i32x8){lo.x, lo.y, lo.z, lo.w, hi.x, hi.y, hi.z, hi.w};
      }
    }
  }

  float rowacc[4][4];
  float colps[4][4];               // [tile][ni], flushed at strip end
#pragma unroll
  for (int a = 0; a < 4; a++)
#pragma unroll
    for (int rr = 0; rr < 4; rr++) { rowacc[a][rr] = 0.f; colps[a][rr] = 0.f; }

#pragma unroll
  for (int jt = 0; jt < 4; ++jt) {
    if (jt < L) {                  // block-uniform guard (L uniform)
      const int j_t = jt0 + jt;

      __syncthreads();             // all waves done reading sB8 (prev tile)

      {                            // stage B(jt), single buffer
        const u8* Bg = Mf8 + (size_t)j_t * 128 * 256;
#pragma unroll
        for (int it = 0; it < 8; ++it) {
          int c = t + 256 * it;
          int row = c >> 4, slot = c & 15;
          int g = slot ^ (row & 15);
          async_copy16(Bg + (size_t)row * 256 + g * 16, (void*)&sB8[c * 16]);
        }
      }
      __syncthreads();             // staging drained (vmcnt(0) at barrier)

      f32x4 acc[4][4];
#pragma unroll
      for (int a = 0; a < 4; a++)
#pragma unroll
        for (int bb = 0; bb < 4; bb++) acc[a][bb] = (f32x4){0.f, 0.f, 0.f, 0.f};

#pragma unroll
      for (int kb = 0; kb < 2; ++kb) {
        i32x8 bfrag[4];
#pragma unroll
        for (int ni = 0; ni < 4; ++ni) {
          const u8* base = sB8 + (wn + ni * 16 + fc) * 256;
          int g0 = kb * 8 + fr * 2;
          int4 lo = *(const int4*)(base + ((g0 ^ fc) * 16));
          int4 hi = *(const int4*)(base + (((g0 + 1) ^ fc) * 16));
          bfrag[ni] = (i32x8){lo.x, lo.y, lo.z, lo.w, hi.x, hi.y, hi.z, hi.w};
        }
#pragma unroll
        for (int mi = 0; mi < 4; mi++)
#pragma unroll
          for (int ni = 0; ni < 4; ni++)
            acc[mi][ni] = __builtin_amdgcn_mfma_scale_f32_16x16x128_f8f6f4(
                afr[mi][kb], bfrag[ni], acc[mi][ni], 0, 0, 0, 0x7F, 0, 0x7F);
      }

      // tile epilogue: exp2-folded, register-only accumulation
#pragma unroll
      for (int mi = 0; mi < 4; mi++) {
#pragma unroll
        for (int ni = 0; ni < 4; ni++) {
          float e0 = hw_exp2(acc[mi][ni][0] * EXP2_SCALE);
          float e1 = hw_exp2(acc[mi][ni][1] * EXP2_SCALE);
          float e2 = hw_exp2(acc[mi][ni][2] * EXP2_SCALE);
          float e3 = hw_exp2(acc[mi][ni][3] * EXP2_SCALE);
          rowacc[mi][0] += e0; rowacc[mi][1] += e1;
          rowacc[mi][2] += e2; rowacc[mi][3] += e3;
          colps[jt][ni] += e0 + e1 + e2 + e3;
        }
      }
    }
  }

  // ---- strip-end flush: all global atomics live here, no barrier after ----
  // column partials (skip the diagonal tile: its transpose IS the row sum)
#pragma unroll
  for (int jt = 0; jt < 4; ++jt) {
    if (jt < L) {
      const int j_t = jt0 + jt;
      if (j_t != i_t) {
        const int j0 = j_t * 128;
#pragma unroll
        for (int ni = 0; ni < 4; ni++) {
          float v = colps[jt][ni];
          v += __shfl_xor(v, 16, 64);
          v += __shfl_xor(v, 32, 64);
          if (fr == 0) atomicAdd(&rsum[j0 + wn + ni * 16 + fc], v);
        }
      }
    }
  }

  // row sums: reduce across the 16 fc lanes, one atomic set
#pragma unroll
  for (int mi = 0; mi < 4; mi++) {
#pragma unroll
    for (int rr = 0; rr < 4; rr++) {
      float v = rowacc[mi][rr];
#pragma unroll
      for (int off = 1; off < 16; off <<= 1) v += __shfl_xor(v, off, 16);
      rowacc[mi][rr] = v;
    }
  }
  if (fc == 0) {
#pragma unroll
    for (int mi = 0; mi < 4; mi++) {
      int rbase = i0 + wm + mi * 16 + fr * 4;
      atomicAdd(&rsum[rbase + 0], rowacc[mi][0]);
      atomicAdd(&rsum[rbase + 1], rowacc[mi][1]);
      atomicAdd(&rsum[rbase + 2], rowacc[mi][2]);
      atomicAdd(&rsum[rbase + 3], rowacc[mi][3]);
    }
  }
}

// ---------------- final loss (4 rows / block), fp8 diagonal ------------------
__global__ void final_loss(const u8* __restrict__ Mf8, const float* __restrict__ rsum,
                           const float* __restrict__ snorm, float* __restrict__ out) {
  int i = blockIdx.x * 4 + (threadIdx.x >> 6);
  int lane = threadIdx.x & 63;
  unsigned int ua = ((const unsigned int*)(Mf8 + (size_t)i * 256))[lane];
  unsigned int ub = ((const unsigned int*)(Mf8 + (size_t)(Nn + i) * 256))[lane];
  float d = 0.f;
#pragma unroll
  for (int e = 0; e < 4; ++e) {
    __hip_fp8_e4m3 qa, qb;
    qa.__x = (ua >> (8 * e)) & 0xFF;
    qb.__x = (ub >> (8 * e)) & 0xFF;
    d += (float)qa * (float)qb;
  }
#pragma unroll
  for (int off = 32; off; off >>= 1) d += __shfl_xor(d, off, 64);
  if (lane == 0) {
    float den1 = rsum[i] - __expf(snorm[i] * INV_TAU);
    float den2 = rsum[Nn + i] - __expf(snorm[Nn + i] * INV_TAU);
    out[i] = 0.5f * (logf(den1) + logf(den2)) - d * INV_TAU;
  }
}

extern "C" void kernel_launch(void* const* d_in, const int* in_sizes, int n_in,
                              void* d_out, int out_size, void* d_ws, size_t ws_size,
                              hipStream_t stream) {
  const float* z1 = (const float*)d_in[0];
  const float* z2 = (const float*)d_in[1];
  const float* W1 = (const float*)d_in[2];
  const float* b1 = (const float*)d_in[3];
  const float* W2 = (const float*)d_in[4];
  const float* b2 = (const float*)d_in[5];
  float* out = (float*)d_out;

  char* ws = (char*)d_ws;
  u8*    Mf8   = (u8*)(ws);                          // 4 MB
  float* rsum  = (float*)(ws + (4u << 20));          // 64 KB
  float* snorm = (float*)(ws + (4u << 20) + 65536);  // 64 KB

  // fused MLP (both layers) + normalize + fp8 emit + snorm + rsum zeroing
  mlp_norm<<<256, 256, 0, stream>>>(z1, z2, W1, b1, W2, b2, Mf8, snorm, rsum);

  // upper-triangle strips of <=4 tiles: 2112 blocks, long strips first
  gram_sym<<<2112, 256, 0, stream>>>(Mf8, rsum);

  final_loss<<<Nn / 4, 256, 0, stream>>>(Mf8, rsum, snorm, out);
}

// Round 6
// 167.428 us; speedup vs baseline: 1.8926x; 1.8926x over previous
//
#include <hip/hip_runtime.h>
#include <hip/hip_bf16.h>
#include <hip/hip_fp8.h>
#include <stdint.h>

#define Nn 8192
#define TWO_N 16384
#define INV_TAU 2.0f
#define EXP2_SCALE 2.885390081777927f   /* INV_TAU * log2(e) */

typedef unsigned short u16;
typedef unsigned char u8;
typedef __bf16 bf16x8 __attribute__((ext_vector_type(8)));
typedef float f32x4 __attribute__((ext_vector_type(4)));
typedef int i32x8 __attribute__((ext_vector_type(8)));

typedef const __attribute__((address_space(1))) void* gas_ptr;
typedef __attribute__((address_space(3))) void* las_ptr;

__device__ __forceinline__ void async_copy16(const void* g, void* l) {
  __builtin_amdgcn_global_load_lds((gas_ptr)g, (las_ptr)l, 16, 0, 0);
}

// v_exp_f32: D = 2^S0 (hardware transcendental)
__device__ __forceinline__ float hw_exp2(float x) {
  return __builtin_amdgcn_exp2f(x);
}

// ---------------- W f32 -> bf16 pre-convert (once, ~256 KB out) -------------
// 64 blocks x 256 thr, 8 elems/thread. Wb[0:65536) = W1, Wb[65536:) = W2.
__global__ __launch_bounds__(256)
void wcvt(const float* __restrict__ W1, const float* __restrict__ W2,
          __bf16* __restrict__ Wb) {
  int i = (blockIdx.x * 256 + threadIdx.x) * 8;
  const float* s = (i < 65536) ? (W1 + i) : (W2 + (i - 65536));
  float4 a0 = *(const float4*)s, a1 = *(const float4*)(s + 4);
  bf16x8 v = {(__bf16)a0.x, (__bf16)a0.y, (__bf16)a0.z, (__bf16)a0.w,
              (__bf16)a1.x, (__bf16)a1.y, (__bf16)a1.z, (__bf16)a1.w};
  *(bf16x8*)&Wb[i] = v;
}

// ---------------- fused MLP + normalize + fp8 emit ---------------------------
// 256 blocks x 64 rows, 4 waves (round-3 structure). v3 change: W staging in
// BOTH layers is now async global_load_lds from pre-converted bf16 W (no VGPR
// round-trip, no cvt chain) -- copies issued first, Z f32->bf16 convert runs
// while the W DMA is in flight. Layout/swizzle of sW is byte-identical.
__global__ __launch_bounds__(256)
void mlp_norm(const float* __restrict__ z1, const float* __restrict__ z2,
              const __bf16* __restrict__ Wb, const float* __restrict__ b1,
              const float* __restrict__ b2,
              u8* __restrict__ Mf8, float* __restrict__ snorm,
              float* __restrict__ rsum) {
  __shared__ __bf16 sZ[64 * 64];    // 8 KB  (layer1 A; reduce scratch later)
  __shared__ __bf16 sW[256 * 64];   // 32 KB (W chunk, both layers)
  __shared__ __bf16 sH[64 * 256];   // 32 KB (H1, full K for layer 2)
  const int bx = blockIdx.x;
  const int i0 = bx * 64;
  const float* Zsrc = (bx < 128) ? (z1 + (size_t)i0 * 256)
                                 : (z2 + (size_t)(i0 - Nn) * 256);
  const int t = threadIdx.x;
  const int lane = t & 63, wave = t >> 6;
  const int wn = wave * 64;
  const int fr = lane >> 4, fc = lane & 15;
  const int sw = fc & 7;

  const __bf16* Wb1 = Wb;
  const __bf16* Wb2 = Wb + 65536;

  if (t < 64) rsum[i0 + t] = 0.f;

  f32x4 acc[4][4];
#pragma unroll
  for (int a = 0; a < 4; a++)
#pragma unroll
    for (int b = 0; b < 4; b++) acc[a][b] = (f32x4){0.f, 0.f, 0.f, 0.f};

  // ---- layer 1 ----
  for (int k0 = 0; k0 < 256; k0 += 64) {
    __syncthreads();
#pragma unroll
    for (int it = 0; it < 8; ++it) {               // W1: 2048 granules, async DMA
      int c = t + 256 * it;
      int row = c >> 3, g = (c & 7) ^ (row & 7);
      async_copy16(Wb1 + (size_t)row * 256 + k0 + g * 8, (void*)&sW[c * 8]);
    }
#pragma unroll
    for (int it = 0; it < 2; ++it) {               // Z: 512 granules (convert)
      int c = t + 256 * it;
      int row = c >> 3, g = (c & 7) ^ (row & 7);
      const float* s = Zsrc + (size_t)row * 256 + k0 + g * 8;
      float4 a0 = *(const float4*)s, a1 = *(const float4*)(s + 4);
      bf16x8 v = {(__bf16)a0.x, (__bf16)a0.y, (__bf16)a0.z, (__bf16)a0.w,
                  (__bf16)a1.x, (__bf16)a1.y, (__bf16)a1.z, (__bf16)a1.w};
      *(bf16x8*)&sZ[c * 8] = v;
    }
    __syncthreads();
#pragma unroll
    for (int ks = 0; ks < 2; ++ks) {
      bf16x8 af[4], bfr[4];
#pragma unroll
      for (int mi = 0; mi < 4; mi++)
        af[mi] = *(const bf16x8*)&sZ[(mi * 16 + fc) * 64 + (((ks * 4 + fr) ^ sw) * 8)];
#pragma unroll
      for (int ni = 0; ni < 4; ni++)
        bfr[ni] = *(const bf16x8*)&sW[(wn + ni * 16 + fc) * 64 + (((ks * 4 + fr) ^ sw) * 8)];
#pragma unroll
      for (int mi = 0; mi < 4; mi++)
#pragma unroll
        for (int ni = 0; ni < 4; ni++)
          acc[mi][ni] = __builtin_amdgcn_mfma_f32_16x16x32_bf16(af[mi], bfr[ni], acc[mi][ni], 0, 0, 0);
    }
  }

  // layer-1 epilogue: bias + elu -> bf16 into sH (granule-xor swizzled rows)
  {
    float bv[4];
#pragma unroll
    for (int ni = 0; ni < 4; ni++) bv[ni] = b1[wn + ni * 16 + fc];
#pragma unroll
    for (int mi = 0; mi < 4; mi++)
#pragma unroll
      for (int ni = 0; ni < 4; ni++) {
        int col = wn + ni * 16 + fc;
        int gc = col >> 3;
#pragma unroll
        for (int r = 0; r < 4; r++) {
          int row = mi * 16 + fr * 4 + r;
          float v = acc[mi][ni][r] + bv[ni];
          v = v > 0.f ? v : (__expf(v) - 1.f);
          int pos = (gc & 24) | ((gc & 7) ^ (row & 7));
          sH[row * 256 + pos * 8 + (col & 7)] = (__bf16)v;
          acc[mi][ni][r] = 0.f;
        }
      }
  }

  // ---- layer 2 (A = sH, resident full-K) ----
  for (int k0 = 0; k0 < 256; k0 += 64) {
    __syncthreads();   // also guarantees: all sH writes done before first read
#pragma unroll
    for (int it = 0; it < 8; ++it) {               // W2: 2048 granules, async DMA
      int c = t + 256 * it;
      int row = c >> 3, g = (c & 7) ^ (row & 7);
      async_copy16(Wb2 + (size_t)row * 256 + k0 + g * 8, (void*)&sW[c * 8]);
    }
    __syncthreads();
    const int kgb = k0 >> 3;
#pragma unroll
    for (int ks = 0; ks < 2; ++ks) {
      bf16x8 af[4], bfr[4];
#pragma unroll
      for (int mi = 0; mi < 4; mi++)
        af[mi] = *(const bf16x8*)&sH[(mi * 16 + fc) * 256 + (kgb + (((ks * 4 + fr) ^ sw))) * 8];
#pragma unroll
      for (int ni = 0; ni < 4; ni++)
        bfr[ni] = *(const bf16x8*)&sW[(wn + ni * 16 + fc) * 64 + (((ks * 4 + fr) ^ sw) * 8)];
#pragma unroll
      for (int mi = 0; mi < 4; mi++)
#pragma unroll
        for (int ni = 0; ni < 4; ni++)
          acc[mi][ni] = __builtin_amdgcn_mfma_f32_16x16x32_bf16(af[mi], bfr[ni], acc[mi][ni], 0, 0, 0);
    }
  }

  // ---- epilogue: bias, cross-wave row-norm, fp8 emit, snorm ----
  float bv[4];
#pragma unroll
  for (int ni = 0; ni < 4; ni++) bv[ni] = b2[wn + ni * 16 + fc];

  __syncthreads();                 // sZ dead; reuse as reduce scratch
  float* red = (float*)sZ;         // [64 rows][4 waves]
  float* red2 = red + 256;

#pragma unroll
  for (int mi = 0; mi < 4; mi++) {
    float ssq[4] = {0.f, 0.f, 0.f, 0.f};
#pragma unroll
    for (int ni = 0; ni < 4; ni++)
#pragma unroll
      for (int r = 0; r < 4; r++) {
        float v = acc[mi][ni][r] + bv[ni];
        acc[mi][ni][r] = v;
        ssq[r] += v * v;
      }
#pragma unroll
    for (int r = 0; r < 4; r++) {
      float v = ssq[r];
#pragma unroll
      for (int off = 1; off < 16; off <<= 1) v += __shfl_xor(v, off, 16);
      if (fc == 0) red[(mi * 16 + fr * 4 + r) * 4 + wave] = v;
    }
  }
  __syncthreads();

#pragma unroll
  for (int mi = 0; mi < 4; mi++) {
    float ssq2[4] = {0.f, 0.f, 0.f, 0.f};
#pragma unroll
    for (int r = 0; r < 4; r++) {
      int row = mi * 16 + fr * 4 + r;
      float ss = red[row * 4] + red[row * 4 + 1] + red[row * 4 + 2] + red[row * 4 + 3];
      float rn = 1.f / fmaxf(sqrtf(ss), 1e-12f);
#pragma unroll
      for (int ni = 0; ni < 4; ni++) {
        float v = acc[mi][ni][r] * rn;
        __hip_fp8_e4m3 q(v);
        Mf8[(size_t)(i0 + row) * 256 + wn + ni * 16 + fc] = q.__x;
        float fv = (float)q;
        ssq2[r] += fv * fv;
      }
    }
#pragma unroll
    for (int r = 0; r < 4; r++) {
      float v = ssq2[r];
#pragma unroll
      for (int off = 1; off < 16; off <<= 1) v += __shfl_xor(v, off, 16);
      if (fc == 0) red2[(mi * 16 + fr * 4 + r) * 4 + wave] = v;
    }
  }
  __syncthreads();
  if (t < 64)
    snorm[i0 + t] = red2[t * 4] + red2[t * 4 + 1] + red2[t * 4 + 2] + red2[t * 4 + 3];
}

// ---------------- symmetric Gram, MX fp8 K=128, A-in-regs, B dbuf ------------
// (round-3 version verbatim: 256 thr / 4 waves, dbuf, launch_bounds(256,2),
//  register-only tile epilogue, atomics at strip end, hw exp2. VGPR 124.
//  round-5's launch_bounds(256,4) forced VGPR=64 -> 400 MB of spill traffic.)
__global__ __launch_bounds__(256, 2)
void gram_sym(const u8* __restrict__ Mf8, float* __restrict__ rsum) {
  __shared__ u8 sB8[2][128 * 256];   // 2 x 32 KB
  const int t = threadIdx.x;
  const int lane = t & 63, wave = t >> 6;
  const int wm = (wave >> 1) * 64, wn = (wave & 1) * 64;
  const int fr = lane >> 4, fc = lane & 15;

  // ---- strip mapping (band closed form), long strips dispatched first ----
  int f = 2111 - blockIdx.x;
  int b = 0;
  while (f >= 2 * (b + 1) * (b + 2)) ++b;
  int rem = f - 2 * b * (b + 1);
  int r = rem / (b + 1);
  int q = rem - r * (b + 1);
  int k = 4 * b + 1 + r;
  const int i_t = 128 - k;
  const int jt0 = i_t + 4 * q;
  const int L = min(4, k - 4 * q);
  const int i0 = i_t * 128;

  // stage B(tile 0) into buffer 0
  {
    const u8* Bg = Mf8 + (size_t)jt0 * 128 * 256;
#pragma unroll
    for (int it = 0; it < 8; ++it) {
      int c = t + 256 * it;
      int row = c >> 4, slot = c & 15;
      int g = slot ^ (row & 15);
      async_copy16(Bg + (size_t)row * 256 + g * 16, (void*)&sB8[0][c * 16]);
    }
  }

  // gather A fragments into registers (L2/L3-resident; once per strip)
  i32x8 afr[4][2];
  {
    const u8* Ag = Mf8 + (size_t)i0 * 256;
#pragma unroll
    for (int mi = 0; mi < 4; ++mi) {
      const u8* rp = Ag + (size_t)(wm + mi * 16 + fc) * 256 + fr * 32;
#pragma unroll
      for (int kb = 0; kb < 2; ++kb) {
        int4 lo = *(const int4*)(rp + kb * 128);
        int4 hi = *(const int4*)(rp + kb * 128 + 16);
        afr[mi][kb] = (i32x8){lo.x, lo.y, lo.z, lo.w, hi.x, hi.y, hi.z, hi.w};
      }
    }
  }

  float rowacc[4][4];
  float colps[4][4];               // [tile][ni], flushed at strip end
#pragma unroll
  for (int a = 0; a < 4; a++)
#pragma unroll
    for (int rr = 0; rr < 4; rr++) { rowacc[a][rr] = 0.f; colps[a][rr] = 0.f; }

#pragma unroll
  for (int jt = 0; jt < 4; ++jt) {
    if (jt < L) {                  // block-uniform guard (L uniform)
      const int j_t = jt0 + jt;
      const u8* sB = &sB8[jt & 1][0];

      __syncthreads();   // drains B(jt) staging (issued >=1 tile ago; landed)

      if (jt + 1 < L) {  // prefetch B(jt+1) behind the barrier
        const u8* Bg = Mf8 + (size_t)(j_t + 1) * 128 * 256;
        u8* dst = &sB8[(jt + 1) & 1][0];
#pragma unroll
        for (int it = 0; it < 8; ++it) {
          int c = t + 256 * it;
          int row = c >> 4, slot = c & 15;
          int g = slot ^ (row & 15);
          async_copy16(Bg + (size_t)row * 256 + g * 16, (void*)&dst[c * 16]);
        }
      }

      f32x4 acc[4][4];
#pragma unroll
      for (int a = 0; a < 4; a++)
#pragma unroll
        for (int bb = 0; bb < 4; bb++) acc[a][bb] = (f32x4){0.f, 0.f, 0.f, 0.f};

#pragma unroll
      for (int kb = 0; kb < 2; ++kb) {
        i32x8 bfrag[4];
#pragma unroll
        for (int ni = 0; ni < 4; ++ni) {
          const u8* base = sB + (wn + ni * 16 + fc) * 256;
          int g0 = kb * 8 + fr * 2;
          int4 lo = *(const int4*)(base + ((g0 ^ fc) * 16));
          int4 hi = *(const int4*)(base + (((g0 + 1) ^ fc) * 16));
          bfrag[ni] = (i32x8){lo.x, lo.y, lo.z, lo.w, hi.x, hi.y, hi.z, hi.w};
        }
#pragma unroll
        for (int mi = 0; mi < 4; mi++)
#pragma unroll
          for (int ni = 0; ni < 4; ni++)
            acc[mi][ni] = __builtin_amdgcn_mfma_scale_f32_16x16x128_f8f6f4(
                afr[mi][kb], bfrag[ni], acc[mi][ni], 0, 0, 0, 0x7F, 0, 0x7F);
      }

      // tile epilogue: exp2-folded, register-only accumulation
#pragma unroll
      for (int mi = 0; mi < 4; mi++) {
#pragma unroll
        for (int ni = 0; ni < 4; ni++) {
          float e0 = hw_exp2(acc[mi][ni][0] * EXP2_SCALE);
          float e1 = hw_exp2(acc[mi][ni][1] * EXP2_SCALE);
          float e2 = hw_exp2(acc[mi][ni][2] * EXP2_SCALE);
          float e3 = hw_exp2(acc[mi][ni][3] * EXP2_SCALE);
          rowacc[mi][0] += e0; rowacc[mi][1] += e1;
          rowacc[mi][2] += e2; rowacc[mi][3] += e3;
          colps[jt][ni] += e0 + e1 + e2 + e3;
        }
      }
    }
  }

  // ---- strip-end flush: all global atomics live here, no barrier after ----
  // column partials (skip the diagonal tile: its transpose IS the row sum)
#pragma unroll
  for (int jt = 0; jt < 4; ++jt) {
    if (jt < L) {
      const int j_t = jt0 + jt;
      if (j_t != i_t) {
        const int j0 = j_t * 128;
#pragma unroll
        for (int ni = 0; ni < 4; ni++) {
          float v = colps[jt][ni];
          v += __shfl_xor(v, 16, 64);
          v += __shfl_xor(v, 32, 64);
          if (fr == 0) atomicAdd(&rsum[j0 + wn + ni * 16 + fc], v);
        }
      }
    }
  }

  // row sums: reduce across the 16 fc lanes, one atomic set
#pragma unroll
  for (int mi = 0; mi < 4; mi++) {
#pragma unroll
    for (int rr = 0; rr < 4; rr++) {
      float v = rowacc[mi][rr];
#pragma unroll
      for (int off = 1; off < 16; off <<= 1) v += __shfl_xor(v, off, 16);
      rowacc[mi][rr] = v;
    }
  }
  if (fc == 0) {
#pragma unroll
    for (int mi = 0; mi < 4; mi++) {
      int rbase = i0 + wm + mi * 16 + fr * 4;
      atomicAdd(&rsum[rbase + 0], rowacc[mi][0]);
      atomicAdd(&rsum[rbase + 1], rowacc[mi][1]);
      atomicAdd(&rsum[rbase + 2], rowacc[mi][2]);
      atomicAdd(&rsum[rbase + 3], rowacc[mi][3]);
    }
  }
}

// ---------------- final loss (4 rows / block), fp8 diagonal ------------------
__global__ void final_loss(const u8* __restrict__ Mf8, const float* __restrict__ rsum,
                           const float* __restrict__ snorm, float* __restrict__ out) {
  int i = blockIdx.x * 4 + (threadIdx.x >> 6);
  int lane = threadIdx.x & 63;
  unsigned int ua = ((const unsigned int*)(Mf8 + (size_t)i * 256))[lane];
  unsigned int ub = ((const unsigned int*)(Mf8 + (size_t)(Nn + i) * 256))[lane];
  float d = 0.f;
#pragma unroll
  for (int e = 0; e < 4; ++e) {
    __hip_fp8_e4m3 qa, qb;
    qa.__x = (ua >> (8 * e)) & 0xFF;
    qb.__x = (ub >> (8 * e)) & 0xFF;
    d += (float)qa * (float)qb;
  }
#pragma unroll
  for (int off = 32; off; off >>= 1) d += __shfl_xor(d, off, 64);
  if (lane == 0) {
    float den1 = rsum[i] - __expf(snorm[i] * INV_TAU);
    float den2 = rsum[Nn + i] - __expf(snorm[Nn + i] * INV_TAU);
    out[i] = 0.5f * (logf(den1) + logf(den2)) - d * INV_TAU;
  }
}

extern "C" void kernel_launch(void* const* d_in, const int* in_sizes, int n_in,
                              void* d_out, int out_size, void* d_ws, size_t ws_size,
                              hipStream_t stream) {
  const float* z1 = (const float*)d_in[0];
  const float* z2 = (const float*)d_in[1];
  const float* W1 = (const float*)d_in[2];
  const float* b1 = (const float*)d_in[3];
  const float* W2 = (const float*)d_in[4];
  const float* b2 = (const float*)d_in[5];
  float* out = (float*)d_out;

  char* ws = (char*)d_ws;
  u8*     Mf8   = (u8*)(ws);                          // 4 MB
  float*  rsum  = (float*)(ws + (4u << 20));          // 64 KB
  float*  snorm = (float*)(ws + (4u << 20) + 65536);  // 64 KB
  __bf16* Wb    = (__bf16*)(ws + (4u << 20) + 131072); // 256 KB (bf16 W1|W2)

  // W f32 -> bf16 once (131072 elems / 8 per thread = 16384 threads)
  wcvt<<<64, 256, 0, stream>>>(W1, W2, Wb);

  // fused MLP (both layers) + normalize + fp8 emit + snorm + rsum zeroing
  mlp_norm<<<256, 256, 0, stream>>>(z1, z2, Wb, b1, b2, Mf8, snorm, rsum);

  // upper-triangle strips of <=4 tiles: 2112 blocks, long strips first
  gram_sym<<<2112, 256, 0, stream>>>(Mf8, rsum);

  final_loss<<<Nn / 4, 256, 0, stream>>>(Mf8, rsum, snorm, out);
}